// Round 4
// baseline (176.273 us; speedup 1.0000x reference)
//
#include <hip/hip_runtime.h>
#include <cmath>

#define Bn 32
#define Hn 512
#define Wn 512
#define PADn 4
#define TW 32
#define TH 32
#define RW (TW + 8)   // 40
#define RH (TH + 8)   // 40

struct GaussW { float g[9]; };

__global__ __launch_bounds__(256, 4) void fuse_loss_kernel(
    const float* __restrict__ vis, const float* __restrict__ ir,
    const float* __restrict__ fus, const float* __restrict__ mask,
    float* __restrict__ out, GaussW gw)
{
    // Union LDS: phase A/B use it as s_in[40][40] float4 (25600 B);
    // after a barrier it is reused as s_h1[40][32] float4 (20480 B) +
    // s_h2[40][32] float2 (10240 B). Total 30720 B -> 4 blocks/CU.
    __shared__ float4 s_buf[1920];          // 30720 B
    float4* s_in = s_buf;                   // [RH][RW]
    float4* s_h1 = s_buf;                   // [RH][TW]
    float2* s_h2 = (float2*)(s_buf + 1280); // [RH][TW]
    __shared__ float s_part[4];

    const int t  = threadIdx.x;
    const int x0 = blockIdx.x * TW;
    const int y0 = blockIdx.y * TH;
    const size_t base = (size_t)blockIdx.z * (size_t)(Hn * Wn);

    const int cx = t & 31;      // column owned by this thread (phases B & C)
    const int r0 = t >> 5;      // base row

    // ---- Phase A: stage halo region (zero padding outside image) ----
    for (int idx = t; idx < RH * RW; idx += 256) {
        int ry = idx / RW, rx = idx - ry * RW;
        int gy = y0 + ry - PADn, gx = x0 + rx - PADn;
        float4 v = make_float4(0.f, 0.f, 0.f, 0.f);
        if ((unsigned)gy < (unsigned)Hn && (unsigned)gx < (unsigned)Wn) {
            size_t o = base + (size_t)gy * Wn + gx;
            v.x = ir[o]; v.y = vis[o]; v.z = fus[o];
        }
        s_in[idx] = v;
    }

    // prefetch mask for this thread's 4 output pixels (overlaps staging)
    float mk[4];
    #pragma unroll
    for (int k = 0; k < 4; ++k) {
        int ty = r0 + 8 * k;
        mk[k] = mask[base + (size_t)(y0 + ty) * Wn + (x0 + cx)];
    }
    __syncthreads();

    // ---- Phase B: horizontal 9-tap pass, results in registers ----
    // thread handles rows r0, r0+8, ..., r0+32 at column cx (5 pixels)
    float r_hb_ir[5], r_hb_vi[5], r_hg_ir[5], r_hg_vi[5], r_hg_i2[5], r_hg_v2[5];
    #pragma unroll
    for (int k = 0; k < 5; ++k) {
        int ry = r0 + 8 * k;
        float hb_ir = 0.f, hb_vi = 0.f;
        float hg_ir = 0.f, hg_vi = 0.f, hg_i2 = 0.f, hg_v2 = 0.f;
        #pragma unroll
        for (int dx = 0; dx < 9; ++dx) {
            float4 v = s_in[ry * RW + cx + dx];
            float di = v.x - v.z;
            float dv = v.y - v.z;
            hb_ir = fmaf(di, di, hb_ir);
            hb_vi = fmaf(dv, dv, hb_vi);
            float g = gw.g[dx];
            hg_ir = fmaf(g, v.x, hg_ir);
            hg_vi = fmaf(g, v.y, hg_vi);
            hg_i2 = fmaf(g, v.x * v.x, hg_i2);
            hg_v2 = fmaf(g, v.y * v.y, hg_v2);
        }
        r_hb_ir[k] = hb_ir; r_hb_vi[k] = hb_vi;
        r_hg_ir[k] = hg_ir; r_hg_vi[k] = hg_vi;
        r_hg_i2[k] = hg_i2; r_hg_v2[k] = hg_v2;
    }
    __syncthreads();   // all s_in reads complete -> safe to overwrite

    #pragma unroll
    for (int k = 0; k < 5; ++k) {
        int ry = r0 + 8 * k;
        s_h1[ry * TW + cx] = make_float4(r_hb_ir[k], r_hb_vi[k], r_hg_ir[k], r_hg_vi[k]);
        s_h2[ry * TW + cx] = make_float2(r_hg_i2[k], r_hg_v2[k]);
    }
    __syncthreads();

    // ---- Phase C: vertical 9-tap pass + selection + partial mean ----
    float acc = 0.f;
    #pragma unroll
    for (int k = 0; k < 4; ++k) {
        int ty = r0 + 8 * k;
        float b_ir = 0.f, b_vi = 0.f;
        float mu_ir = 0.f, mu_vi = 0.f, m2_ir = 0.f, m2_vi = 0.f;
        #pragma unroll
        for (int dy = 0; dy < 9; ++dy) {
            float4 h1 = s_h1[(ty + dy) * TW + cx];
            float2 h2 = s_h2[(ty + dy) * TW + cx];
            b_ir += h1.x;
            b_vi += h1.y;
            float g = gw.g[dy];
            mu_ir = fmaf(g, h1.z, mu_ir);
            mu_vi = fmaf(g, h1.w, mu_vi);
            m2_ir = fmaf(g, h2.x, m2_ir);
            m2_vi = fmaf(g, h2.y, m2_vi);
        }
        float mse_ir = b_ir * (1.f / 81.f);
        float mse_vi = b_vi * (1.f / 81.f);
        float var_ir = m2_ir - mu_ir * mu_ir;
        float var_vi = m2_vi - mu_vi * mu_vi;
        float m1 = (var_ir - var_vi > 0.f) ? 1.f : 0.f;
        float mir = (m1 + mk[k] > 0.f) ? 1.f : 0.f;
        acc += mir * mse_ir + (1.f - mir) * mse_vi;
    }

    // ---- block reduction, one atomicAdd per block ----
    #pragma unroll
    for (int off = 32; off > 0; off >>= 1)
        acc += __shfl_down(acc, off, 64);
    int wave = t >> 6, lane = t & 63;
    if (lane == 0) s_part[wave] = acc;
    __syncthreads();
    if (t == 0) {
        float s = s_part[0] + s_part[1] + s_part[2] + s_part[3];
        atomicAdd(out, s * (1.f / ((float)Bn * (float)Hn * (float)Wn)));
    }
}

extern "C" void kernel_launch(void* const* d_in, const int* in_sizes, int n_in,
                              void* d_out, int out_size, void* d_ws, size_t ws_size,
                              hipStream_t stream) {
    const float* vis  = (const float*)d_in[0];
    const float* ir   = (const float*)d_in[1];
    const float* fus  = (const float*)d_in[2];
    const float* mask = (const float*)d_in[3];
    float* out = (float*)d_out;

    GaussW gw;
    double g[9], s = 0.0;
    for (int i = 0; i < 9; ++i) {
        int x = i - 4;
        g[i] = exp(-(double)(x * x) / 4.5);
        s += g[i];
    }
    for (int i = 0; i < 9; ++i) gw.g[i] = (float)(g[i] / s);

    hipMemsetAsync(d_out, 0, sizeof(float), stream);
    dim3 grid(Wn / TW, Hn / TH, Bn);
    fuse_loss_kernel<<<grid, 256, 0, stream>>>(vis, ir, fus, mask, out, gw);
}

// Round 5
// 130.279 us; speedup vs baseline: 1.3530x; 1.3530x over previous
//
#include <hip/hip_runtime.h>
#include <cmath>

#define Bn 32
#define Hn 512
#define Wn 512
#define PADn 4
#define TW 32
#define TH 32
#define RW (TW + 8)   // 40
#define RH (TH + 8)   // 40

struct GaussW { float g[9]; };

// launch_bounds(256,2): R4 showed (256,4) makes the allocator spill 30
// accumulators to scratch (WRITE_SIZE 0.25MB->344MB, dur +33us). (256,2)
// empirically gives ~88 VGPR, no spill; LDS 30.7KB then allows 5 blocks/CU.
__global__ __launch_bounds__(256, 2) void fuse_loss_kernel(
    const float* __restrict__ vis, const float* __restrict__ ir,
    const float* __restrict__ fus, const float* __restrict__ mask,
    float* __restrict__ out, GaussW gw)
{
    // Union LDS: phase A/B use it as s_in[40][40] float4 (25600 B);
    // after a barrier it is reused as s_h1[40][32] float4 (20480 B) +
    // s_h2[40][32] float2 (10240 B). Total 30720 B.
    __shared__ float4 s_buf[1920];          // 30720 B
    float4* s_in = s_buf;                   // [RH][RW]
    float4* s_h1 = s_buf;                   // [RH][TW]
    float2* s_h2 = (float2*)(s_buf + 1280); // [RH][TW]
    __shared__ float s_part[4];

    const int t  = threadIdx.x;
    const int x0 = blockIdx.x * TW;
    const int y0 = blockIdx.y * TH;
    const size_t base = (size_t)blockIdx.z * (size_t)(Hn * Wn);

    const int cx = t & 31;      // column owned by this thread (phases B & C)
    const int r0 = t >> 5;      // base row

    // ---- Phase A: stage halo region (zero padding outside image) ----
    for (int idx = t; idx < RH * RW; idx += 256) {
        int ry = idx / RW, rx = idx - ry * RW;
        int gy = y0 + ry - PADn, gx = x0 + rx - PADn;
        float4 v = make_float4(0.f, 0.f, 0.f, 0.f);
        if ((unsigned)gy < (unsigned)Hn && (unsigned)gx < (unsigned)Wn) {
            size_t o = base + (size_t)gy * Wn + gx;
            v.x = ir[o]; v.y = vis[o]; v.z = fus[o];
        }
        s_in[idx] = v;
    }

    // prefetch mask for this thread's 4 output pixels (overlaps staging)
    float mk[4];
    #pragma unroll
    for (int k = 0; k < 4; ++k) {
        int ty = r0 + 8 * k;
        mk[k] = mask[base + (size_t)(y0 + ty) * Wn + (x0 + cx)];
    }
    __syncthreads();

    // ---- Phase B: horizontal 9-tap pass, results in registers ----
    // thread handles rows r0, r0+8, ..., r0+32 at column cx (5 pixels)
    float r_hb_ir[5], r_hb_vi[5], r_hg_ir[5], r_hg_vi[5], r_hg_i2[5], r_hg_v2[5];
    #pragma unroll
    for (int k = 0; k < 5; ++k) {
        int ry = r0 + 8 * k;
        float hb_ir = 0.f, hb_vi = 0.f;
        float hg_ir = 0.f, hg_vi = 0.f, hg_i2 = 0.f, hg_v2 = 0.f;
        #pragma unroll
        for (int dx = 0; dx < 9; ++dx) {
            float4 v = s_in[ry * RW + cx + dx];
            float di = v.x - v.z;
            float dv = v.y - v.z;
            hb_ir = fmaf(di, di, hb_ir);
            hb_vi = fmaf(dv, dv, hb_vi);
            float g = gw.g[dx];
            hg_ir = fmaf(g, v.x, hg_ir);
            hg_vi = fmaf(g, v.y, hg_vi);
            hg_i2 = fmaf(g, v.x * v.x, hg_i2);
            hg_v2 = fmaf(g, v.y * v.y, hg_v2);
        }
        r_hb_ir[k] = hb_ir; r_hb_vi[k] = hb_vi;
        r_hg_ir[k] = hg_ir; r_hg_vi[k] = hg_vi;
        r_hg_i2[k] = hg_i2; r_hg_v2[k] = hg_v2;
    }
    __syncthreads();   // all s_in reads complete -> safe to overwrite

    #pragma unroll
    for (int k = 0; k < 5; ++k) {
        int ry = r0 + 8 * k;
        s_h1[ry * TW + cx] = make_float4(r_hb_ir[k], r_hb_vi[k], r_hg_ir[k], r_hg_vi[k]);
        s_h2[ry * TW + cx] = make_float2(r_hg_i2[k], r_hg_v2[k]);
    }
    __syncthreads();

    // ---- Phase C: vertical 9-tap pass + selection + partial mean ----
    float acc = 0.f;
    #pragma unroll
    for (int k = 0; k < 4; ++k) {
        int ty = r0 + 8 * k;
        float b_ir = 0.f, b_vi = 0.f;
        float mu_ir = 0.f, mu_vi = 0.f, m2_ir = 0.f, m2_vi = 0.f;
        #pragma unroll
        for (int dy = 0; dy < 9; ++dy) {
            float4 h1 = s_h1[(ty + dy) * TW + cx];
            float2 h2 = s_h2[(ty + dy) * TW + cx];
            b_ir += h1.x;
            b_vi += h1.y;
            float g = gw.g[dy];
            mu_ir = fmaf(g, h1.z, mu_ir);
            mu_vi = fmaf(g, h1.w, mu_vi);
            m2_ir = fmaf(g, h2.x, m2_ir);
            m2_vi = fmaf(g, h2.y, m2_vi);
        }
        float mse_ir = b_ir * (1.f / 81.f);
        float mse_vi = b_vi * (1.f / 81.f);
        float var_ir = m2_ir - mu_ir * mu_ir;
        float var_vi = m2_vi - mu_vi * mu_vi;
        float m1 = (var_ir - var_vi > 0.f) ? 1.f : 0.f;
        float mir = (m1 + mk[k] > 0.f) ? 1.f : 0.f;
        acc += mir * mse_ir + (1.f - mir) * mse_vi;
    }

    // ---- block reduction, one atomicAdd per block ----
    #pragma unroll
    for (int off = 32; off > 0; off >>= 1)
        acc += __shfl_down(acc, off, 64);
    int wave = t >> 6, lane = t & 63;
    if (lane == 0) s_part[wave] = acc;
    __syncthreads();
    if (t == 0) {
        float s = s_part[0] + s_part[1] + s_part[2] + s_part[3];
        atomicAdd(out, s * (1.f / ((float)Bn * (float)Hn * (float)Wn)));
    }
}

extern "C" void kernel_launch(void* const* d_in, const int* in_sizes, int n_in,
                              void* d_out, int out_size, void* d_ws, size_t ws_size,
                              hipStream_t stream) {
    const float* vis  = (const float*)d_in[0];
    const float* ir   = (const float*)d_in[1];
    const float* fus  = (const float*)d_in[2];
    const float* mask = (const float*)d_in[3];
    float* out = (float*)d_out;

    GaussW gw;
    double g[9], s = 0.0;
    for (int i = 0; i < 9; ++i) {
        int x = i - 4;
        g[i] = exp(-(double)(x * x) / 4.5);
        s += g[i];
    }
    for (int i = 0; i < 9; ++i) gw.g[i] = (float)(g[i] / s);

    hipMemsetAsync(d_out, 0, sizeof(float), stream);
    dim3 grid(Wn / TW, Hn / TH, Bn);
    fuse_loss_kernel<<<grid, 256, 0, stream>>>(vis, ir, fus, mask, out, gw);
}